// Round 8
// baseline (545.345 us; speedup 1.0000x reference)
//
#include <hip/hip_runtime.h>

typedef __bf16 bf16;
typedef __bf16 bf16x4 __attribute__((ext_vector_type(4)));
typedef __bf16 bf16x8 __attribute__((ext_vector_type(8)));
typedef float f32x4 __attribute__((ext_vector_type(4)));

#define MFMA16(a, b, c) __builtin_amdgcn_mfma_f32_16x16x32_bf16(a, b, c, 0, 0, 0)

// Problem constants: B=8, N=4096, M=256, DIM=256, HEADS=8, DIM_HEAD=64, INNER=512
// exp(S*scale) = exp2(S * 0.125 * log2(e))
#define CEXP 0.18033688011112042f

// async global->LDS, 16B per lane; lds base wave-uniform (HW adds lane*16)
__device__ inline void gload16(const bf16* g, bf16* l) {
  __builtin_amdgcn_global_load_lds(
      (const __attribute__((address_space(1))) unsigned int*)g,
      (__attribute__((address_space(3))) unsigned int*)l, 16, 0, 0);
}

// ---------------------------------------------------------------------------
// Weight pre-transpose + downcast: W[K,N] fp32 -> WT[N,K] bf16 (10 matrices)
// ---------------------------------------------------------------------------
struct WTArgs {
  const float* src[10];
  bf16* dst[10];
  int K[10];
  int N[10];
};

__global__ __launch_bounds__(256) void wtrans_kernel(WTArgs args) {
  const int z = blockIdx.z;
  const int K = args.K[z], N = args.N[z];
  const int k0 = blockIdx.x * 64, n0 = blockIdx.y * 64;
  if (k0 >= K || n0 >= N) return;
  __shared__ float t[64][65];
  const int tx = threadIdx.x & 63, ty = threadIdx.x >> 6;
  const float* __restrict__ src = args.src[z];
  bf16* __restrict__ dst = args.dst[z];
#pragma unroll
  for (int i = 0; i < 16; ++i)
    t[ty + i * 4][tx] = src[(size_t)(k0 + ty + i * 4) * N + n0 + tx];
  __syncthreads();
#pragma unroll
  for (int i = 0; i < 16; ++i)
    dst[(size_t)(n0 + ty + i * 4) * K + k0 + tx] = (bf16)t[tx][ty + i * 4];
}

// ---------------------------------------------------------------------------
// xq[b][n][c] = feat[b][n][c] + pos[b][c][n]  (fp32 in, bf16 out)
// ---------------------------------------------------------------------------
__global__ __launch_bounds__(256) void prep_xq_kernel(
    const float* __restrict__ feat, const float* __restrict__ pos,
    bf16* __restrict__ xq) {
  const int n0 = blockIdx.x * 64;
  const int c0 = blockIdx.y * 64;
  const int b = blockIdx.z;
  __shared__ float t[64][65];
  const int tx = threadIdx.x & 63, ty = threadIdx.x >> 6;
#pragma unroll
  for (int i = 0; i < 16; ++i) {
    int c = ty + i * 4;
    t[c][tx] = pos[((size_t)b * 256 + c0 + c) * 4096 + n0 + tx];
  }
  __syncthreads();
#pragma unroll
  for (int i = 0; i < 16; ++i) {
    int n = ty + i * 4;
    size_t off = ((size_t)b * 4096 + n0 + n) * 256 + c0 + tx;
    xq[off] = (bf16)(feat[off] + t[tx][n]);
  }
}

// xk = center + center_pos (fp32 in, bf16 out, vectorized x4)
__global__ __launch_bounds__(256) void addvec_kernel(
    const float* __restrict__ a, const float* __restrict__ b,
    bf16* __restrict__ o, int n4) {
  int i = blockIdx.x * 256 + threadIdx.x;
  if (i < n4) {
    f32x4 x = ((const f32x4*)a)[i];
    f32x4 y = ((const f32x4*)b)[i];
    bf16x4 z;
#pragma unroll
    for (int j = 0; j < 4; ++j) z[j] = (bf16)(x[j] + y[j]);
    ((bf16x4*)o)[i] = z;
  }
}

// 8 contiguous fp32 -> bf16x8
__device__ inline bf16x8 ldA8f(const float* p) {
  f32x4 u = *(const f32x4*)p;
  f32x4 v = *((const f32x4*)p + 1);
  bf16x8 o;
#pragma unroll
  for (int i = 0; i < 4; ++i) {
    o[i] = (bf16)u[i];
    o[4 + i] = (bf16)v[i];
  }
  return o;
}

// ---------------------------------------------------------------------------
// GEMM body: C[m0.., n0..] tile of A[M,K] @ BT[N,K]^T. 128x128 tile, 4 waves,
// BK=32, global_load_lds for bf16 operands, VGPR-convert for fp32.
// EPI: 0=none, 1=relu, 2=+resid, 3=+bias+resid.
// ---------------------------------------------------------------------------
template <int EPI, typename TO, typename TR, typename TA, typename TB>
__device__ __forceinline__ void gemm_body(
    const TA* __restrict__ A, const TB* __restrict__ BT, TO* __restrict__ C,
    const TR* __restrict__ resid, const float* __restrict__ bias, int N, int K,
    int m0, int n0, bf16* Al, bf16* Bl) {
  const int tid = threadIdx.x;
  const int lane = tid & 63;
  const int w = tid >> 6;
  const int wr = (w >> 1) * 64, wc = (w & 1) * 64;
  const int l15 = lane & 15, quad = lane >> 4;
  constexpr bool A_BF16 = (sizeof(TA) == 2);
  constexpr bool B_BF16 = (sizeof(TB) == 2);

  f32x4 acc[4][4];
#pragma unroll
  for (int i = 0; i < 4; ++i)
#pragma unroll
    for (int j = 0; j < 4; ++j) acc[i][j] = (f32x4){0.f, 0.f, 0.f, 0.f};

  for (int k0 = 0; k0 < K; k0 += 32) {
    if constexpr (B_BF16) {
#pragma unroll
      for (int c = 0; c < 2; ++c) {
        int r0 = w * 32 + c * 16;
        gload16((const bf16*)BT + (size_t)(n0 + r0 + (lane >> 2)) * K + k0 +
                    (lane & 3) * 8,
                Bl + r0 * 32);
      }
    } else {
#pragma unroll
      for (int c = 0; c < 2; ++c) {
        int idx = tid + c * 256;
        int row = idx >> 2;
        int ko = (idx & 3) * 8;
        *(bf16x8*)(Bl + row * 32 + ko) =
            ldA8f((const float*)BT + (size_t)(n0 + row) * K + k0 + ko);
      }
    }
    if constexpr (A_BF16) {
#pragma unroll
      for (int c = 0; c < 2; ++c) {
        int r0 = w * 32 + c * 16;
        gload16((const bf16*)A + (size_t)(m0 + r0 + (lane >> 2)) * K + k0 +
                    (lane & 3) * 8,
                Al + r0 * 32);
      }
    } else {
#pragma unroll
      for (int c = 0; c < 2; ++c) {
        int idx = tid + c * 256;
        int row = idx >> 2;
        int ko = (idx & 3) * 8;
        *(bf16x8*)(Al + row * 32 + ko) =
            ldA8f((const float*)A + (size_t)(m0 + row) * K + k0 + ko);
      }
    }
    __syncthreads();
    bf16x8 fa[4], fb[4];
#pragma unroll
    for (int i = 0; i < 4; ++i) {
      fa[i] = *(const bf16x8*)(Al + (wr + i * 16 + l15) * 32 + quad * 8);
      fb[i] = *(const bf16x8*)(Bl + (wc + i * 16 + l15) * 32 + quad * 8);
    }
#pragma unroll
    for (int i = 0; i < 4; ++i)
#pragma unroll
      for (int j = 0; j < 4; ++j)
        acc[i][j] = MFMA16(fa[i], fb[j], acc[i][j]);
    __syncthreads();
  }

#pragma unroll
  for (int i = 0; i < 4; ++i) {
#pragma unroll
    for (int r = 0; r < 4; ++r) {
      int row = m0 + wr + i * 16 + quad * 4 + r;
      size_t rb = (size_t)row * N + n0 + wc;
#pragma unroll
      for (int j = 0; j < 4; ++j) {
        int col = n0 + wc + j * 16 + l15;
        float v = acc[i][j][r];
        if constexpr (EPI == 1) v = fmaxf(v, 0.f);
        if constexpr (EPI == 2) v += (float)resid[rb + j * 16 + l15];
        if constexpr (EPI == 3)
          v += bias[col] + (float)resid[rb + j * 16 + l15];
        C[rb + j * 16 + l15] = (TO)v;
      }
    }
  }
}

// Dual-problem GEMM, split along grid.x (same N, K for both problems).
template <int EPI, typename TO, typename TR, typename TA, typename TB>
__global__ __launch_bounds__(256) void gemm_dx_kernel(
    const TA* Af, const TB* BTf, TO* Cf, const TR* rf, const float* bf_,
    const TA* Ac, const TB* BTc, TO* Cc, const TR* rc, const float* bc_,
    int fblocks, int N, int K) {
  __shared__ bf16 Al[128 * 32];
  __shared__ bf16 Bl[128 * 32];
  int bx = blockIdx.x;
  if (bx < fblocks)
    gemm_body<EPI, TO, TR, TA, TB>(Af, BTf, Cf, rf, bf_, N, K, bx * 128,
                                   blockIdx.y * 128, Al, Bl);
  else
    gemm_body<EPI, TO, TR, TA, TB>(Ac, BTc, Cc, rc, bc_, N, K,
                                   (bx - fblocks) * 128, blockIdx.y * 128, Al,
                                   Bl);
}

// Dual-problem GEMM, split along grid.y (same M, K; different N).
template <int EPI, typename TO, typename TR, typename TA, typename TB>
__global__ __launch_bounds__(256) void gemm_dy_kernel(
    const TA* Af, const TB* BTf, TO* Cf, const TA* Ac, const TB* BTc, TO* Cc,
    int fnblocks, int Nf, int Nc, int K) {
  __shared__ bf16 Al[128 * 32];
  __shared__ bf16 Bl[128 * 32];
  int by = blockIdx.y;
  if (by < fnblocks)
    gemm_body<EPI, TO, TR, TA, TB>(Af, BTf, Cf, nullptr, nullptr, Nf, K,
                                   blockIdx.x * 128, by * 128, Al, Bl);
  else
    gemm_body<EPI, TO, TR, TA, TB>(Ac, BTc, Cc, nullptr, nullptr, Nc, K,
                                   blockIdx.x * 128, (by - fnblocks) * 128, Al,
                                   Bl);
}

// ---------------------------------------------------------------------------
// attall: the ENTIRE attention in one kernel, 1 barrier per block.
// Grid (ns=8 n-splits of 512, bh=64). k[256][64] staged to LDS once.
// Per 64-n chunk (8 per block), all waves independent (wave-private LDS only):
//  S-side (wave w, its 16-n stripe): S = q@k^T via MFMA; E=exp -> Pl[w];
//    O1 += P @ v2 (B-frags straight from global v2t[d][m]); rowsum in regs;
//    normalized af store at chunk end (softmax over m path).
//  ST-side (wave w, its 64-m quarter): S^T via swapped MFMA(k,q) over ALL 64
//    chunk-n; ET=exp -> per-wave PTw (A-layout round-trip, same-wave DS is
//    in-order); O2 += ET @ v1 (B-frags from global v1t[d][n]); colsum in regs.
// O2/colsum partials per (ns,bh) -> o2p (d_out scratch) / colp; o2red reduces.
// LDS 64.5KB -> 2 blocks/CU.
// ---------------------------------------------------------------------------
__global__ __launch_bounds__(256) void attall_kernel(
    const bf16* __restrict__ q, const bf16* __restrict__ kk,
    const bf16* __restrict__ v1t, const bf16* __restrict__ v2t,
    bf16* __restrict__ af, float* __restrict__ o2p, float* __restrict__ colp) {
  const int ns = blockIdx.x;  // 8
  const int bh = blockIdx.y;  // 64
  const int b = bh >> 3, h = bh & 7;
  const int tid = threadIdx.x;
  const int lane = tid & 63;
  const int w = tid >> 6;
  const int l15 = lane & 15, quad = lane >> 4;

  __shared__ bf16 klds[256 * 72];   // 36864B [m][d]
  __shared__ bf16 Pl[4][16 * 72];   // 9216B per-wave E [n16][m64]
  __shared__ bf16 PTw[4][32 * 72];  // 18432B per-wave ET [m32][n64]

  // stage k slice [256 m][64 d] — the ONLY barrier-protected staging
#pragma unroll
  for (int c = 0; c < 8; ++c) {
    int idx = tid + c * 256;
    int m = idx >> 3, dc = (idx & 7) * 8;
    *(bf16x8*)(klds + m * 72 + dc) =
        *(const bf16x8*)(kk + ((size_t)(b * 256 + m)) * 512 + h * 64 + dc);
  }
  __syncthreads();

  const bf16* v1b = v1t + (size_t)(h * 64) * 32768 + b * 4096 + ns * 512;
  const bf16* v2b = v2t + (size_t)(h * 64) * 2048 + b * 256;

  f32x4 o2acc[4][4];  // [mt (within wave's m-quarter)][dt]
#pragma unroll
  for (int i = 0; i < 4; ++i)
#pragma unroll
    for (int j = 0; j < 4; ++j) o2acc[i][j] = (f32x4){0.f, 0.f, 0.f, 0.f};
  float cs[16];  // colsum partials [mt][r]
#pragma unroll
  for (int i = 0; i < 16; ++i) cs[i] = 0.f;

  for (int ch = 0; ch < 8; ++ch) {
    const int nb = ns * 512 + ch * 64;
    // q fragments for all 4 stripes of this chunk
    bf16x8 aT0[4], aT1[4];
#pragma unroll
    for (int it = 0; it < 4; ++it) {
      const bf16* qp =
          q + ((size_t)(b * 4096 + nb + it * 16 + l15)) * 512 + h * 64 +
          quad * 8;
      aT0[it] = *(const bf16x8*)qp;
      aT1[it] = *(const bf16x8*)(qp + 32);
    }
    // v1 B-fragments for this chunk (reused across both m-halves)
    bf16x8 vb1[2][4];
#pragma unroll
    for (int ks = 0; ks < 2; ++ks)
#pragma unroll
      for (int dt = 0; dt < 4; ++dt)
        vb1[ks][dt] = *(const bf16x8*)(v1b + (size_t)(dt * 16 + l15) * 32768 +
                                       ch * 64 + ks * 32 + quad * 8);

    // ---------------- S side: softmax over m -> O1 ----------------
    f32x4 o1acc[4];
#pragma unroll
    for (int i = 0; i < 4; ++i) o1acc[i] = (f32x4){0.f, 0.f, 0.f, 0.f};
    float rs[4] = {0.f, 0.f, 0.f, 0.f};
#pragma unroll
    for (int mq = 0; mq < 4; ++mq) {
#pragma unroll
      for (int mt = 0; mt < 4; ++mt) {
        const bf16* kp = klds + (mq * 64 + mt * 16 + l15) * 72 + quad * 8;
        bf16x8 b0 = *(const bf16x8*)kp;
        bf16x8 b1 = *(const bf16x8*)(kp + 32);
        f32x4 s = (f32x4){0.f, 0.f, 0.f, 0.f};
        s = MFMA16(aT0[w], b0, s);
        s = MFMA16(aT1[w], b1, s);
#pragma unroll
        for (int r = 0; r < 4; ++r) {
          float e = exp2f(s[r] * CEXP);
          rs[r] += e;
          Pl[w][(quad * 4 + r) * 72 + mt * 16 + l15] = (bf16)e;
        }
      }
      asm volatile("" ::: "memory");
#pragma unroll
      for (int ks = 0; ks < 2; ++ks) {
        bf16x8 pa = *(const bf16x8*)(Pl[w] + l15 * 72 + ks * 32 + quad * 8);
#pragma unroll
        for (int dt = 0; dt < 4; ++dt) {
          bf16x8 vb2 = *(const bf16x8*)(v2b + (size_t)(dt * 16 + l15) * 2048 +
                                        mq * 64 + ks * 32 + quad * 8);
          o1acc[dt] = MFMA16(pa, vb2, o1acc[dt]);
        }
      }
      asm volatile("" ::: "memory");
    }
    // rowsum (over all 256 m) -> normalize, store af
    float inv[4];
#pragma unroll
    for (int r = 0; r < 4; ++r) {
      float v = rs[r];
      v += __shfl_xor(v, 1, 64);
      v += __shfl_xor(v, 2, 64);
      v += __shfl_xor(v, 4, 64);
      v += __shfl_xor(v, 8, 64);
      inv[r] = 1.f / v;
    }
#pragma unroll
    for (int dt = 0; dt < 4; ++dt) {
#pragma unroll
      for (int r = 0; r < 4; ++r) {
        int n = nb + w * 16 + quad * 4 + r;
        af[((size_t)(b * 4096 + n)) * 512 + h * 64 + dt * 16 + l15] =
            (bf16)(o1acc[dt][r] * inv[r]);
      }
    }

    // ---------------- ST side: wave's m-quarter, all 64 n -> O2 ----------
#pragma unroll
    for (int mh = 0; mh < 2; ++mh) {
#pragma unroll
      for (int it = 0; it < 4; ++it) {
#pragma unroll
        for (int m2 = 0; m2 < 2; ++m2) {
          int mt = mh * 2 + m2;
          const bf16* kp = klds + (w * 64 + mt * 16 + l15) * 72 + quad * 8;
          bf16x8 b0 = *(const bf16x8*)kp;
          bf16x8 b1 = *(const bf16x8*)(kp + 32);
          f32x4 st = (f32x4){0.f, 0.f, 0.f, 0.f};
          st = MFMA16(b0, aT0[it], st);  // S^T[m][n]
          st = MFMA16(b1, aT1[it], st);
#pragma unroll
          for (int r = 0; r < 4; ++r) {
            float et = exp2f(st[r] * CEXP);
            cs[mt * 4 + r] += et;
            PTw[w][(m2 * 16 + quad * 4 + r) * 72 + it * 16 + l15] = (bf16)et;
          }
        }
      }
      asm volatile("" ::: "memory");
#pragma unroll
      for (int m2 = 0; m2 < 2; ++m2) {
        int mt = mh * 2 + m2;
#pragma unroll
        for (int ks = 0; ks < 2; ++ks) {
          bf16x8 pa2 =
              *(const bf16x8*)(PTw[w] + (m2 * 16 + l15) * 72 + ks * 32 +
                               quad * 8);
#pragma unroll
          for (int dt = 0; dt < 4; ++dt)
            o2acc[mt][dt] = MFMA16(pa2, vb1[ks][dt], o2acc[mt][dt]);
        }
      }
      asm volatile("" ::: "memory");
    }
  }

  // ---- epilogues: colsum + O2 partials (coalesced, no atomics) ----
#pragma unroll
  for (int t = 0; t < 16; ++t) {
    float v = cs[t];
    v += __shfl_xor(v, 1, 64);
    v += __shfl_xor(v, 2, 64);
    v += __shfl_xor(v, 4, 64);
    v += __shfl_xor(v, 8, 64);
    if (l15 == 0)
      colp[((size_t)ns * 64 + bh) * 256 + w * 64 + (t >> 2) * 16 + quad * 4 +
           (t & 3)] = v;
  }
  float* ob = o2p + ((size_t)ns * 64 + bh) * 16384;  // [256 m][64 d]
#pragma unroll
  for (int mt = 0; mt < 4; ++mt)
#pragma unroll
    for (int dt = 0; dt < 4; ++dt)
#pragma unroll
      for (int r = 0; r < 4; ++r)
        ob[(w * 64 + mt * 16 + quad * 4 + r) * 64 + dt * 16 + l15] =
            o2acc[mt][dt][r];
}

// acm[b][m][h*64+d] = (sum_ns o2p[ns][bh][m][d]) / (sum_ns colp[ns][bh][m])
__global__ __launch_bounds__(256) void o2red_kernel(
    const float* __restrict__ o2p, const float* __restrict__ colp,
    bf16* __restrict__ acm) {
  int idx = blockIdx.x * 256 + threadIdx.x;  // [b][m][h][d]
  int d = idx & 63;
  int h = (idx >> 6) & 7;
  int m = (idx >> 9) & 255;
  int b = idx >> 17;
  int bh = b * 8 + h;
  float v = 0.f, c = 0.f;
#pragma unroll
  for (int p = 0; p < 8; ++p) {
    v += o2p[(((size_t)p * 64 + bh) * 256 + m) * 64 + d];
    c += colp[((size_t)p * 64 + bh) * 256 + m];
  }
  acm[idx] = (bf16)(v / c);
}

// ---------------------------------------------------------------------------
// Dual LayerNorm over last dim (256): one wave/row; rows<32768 feat else ctr.
// ---------------------------------------------------------------------------
__global__ __launch_bounds__(256) void ln_dual_kernel(
    const bf16* __restrict__ xf, const bf16* __restrict__ xc,
    const float* __restrict__ w1, const float* __restrict__ b1,
    const float* __restrict__ w2, const float* __restrict__ b2,
    bf16* __restrict__ yf, bf16* __restrict__ yc) {
  int wave = threadIdx.x >> 6;
  int lane = threadIdx.x & 63;
  int row = blockIdx.x * 4 + wave;
  const bf16* x;
  const float *wv, *bv;
  bf16* y;
  if (row < 32768) {
    x = xf; wv = w1; bv = b1; y = yf;
  } else {
    row -= 32768; x = xc; wv = w2; bv = b2; y = yc;
  }
  const bf16* xr = x + (size_t)row * 256;
  bf16x4 v = *(const bf16x4*)(xr + lane * 4);
  float f0 = v[0], f1 = v[1], f2 = v[2], f3 = v[3];
  float s = f0 + f1 + f2 + f3;
  float ss = f0 * f0 + f1 * f1 + f2 * f2 + f3 * f3;
#pragma unroll
  for (int m = 1; m < 64; m <<= 1) {
    s += __shfl_xor(s, m, 64);
    ss += __shfl_xor(ss, m, 64);
  }
  float mean = s * (1.f / 256.f);
  float var = ss * (1.f / 256.f) - mean * mean;
  float rstd = rsqrtf(var + 1e-5f);
  f32x4 wq = *(const f32x4*)(wv + lane * 4);
  f32x4 bq = *(const f32x4*)(bv + lane * 4);
  bf16x4 o;
  o[0] = (bf16)((f0 - mean) * rstd * wq[0] + bq[0]);
  o[1] = (bf16)((f1 - mean) * rstd * wq[1] + bq[1]);
  o[2] = (bf16)((f2 - mean) * rstd * wq[2] + bq[2]);
  o[3] = (bf16)((f3 - mean) * rstd * wq[3] + bq[3]);
  *(bf16x4*)(y + (size_t)row * 256 + lane * 4) = o;
}

// ---------------------------------------------------------------------------
extern "C" void kernel_launch(void* const* d_in, const int* in_sizes, int n_in,
                              void* d_out, int out_size, void* d_ws,
                              size_t ws_size, hipStream_t stream) {
  const float* feat = (const float*)d_in[0];
  const float* center = (const float*)d_in[1];
  const float* pos = (const float*)d_in[2];
  const float* cpos = (const float*)d_in[3];
  const float* Wq = (const float*)d_in[4];
  const float* Wk = (const float*)d_in[5];
  const float* Wv1 = (const float*)d_in[6];
  const float* Wv2 = (const float*)d_in[7];
  const float* Wo1 = (const float*)d_in[8];
  const float* Wo2 = (const float*)d_in[9];
  const float* ln1w = (const float*)d_in[10];
  const float* ln1b = (const float*)d_in[11];
  const float* ln2w = (const float*)d_in[12];
  const float* ln2b = (const float*)d_in[13];
  const float* f1W1 = (const float*)d_in[14];
  const float* f1W2 = (const float*)d_in[15];
  const float* f1b2 = (const float*)d_in[16];
  const float* f2W1 = (const float*)d_in[17];
  const float* f2W2 = (const float*)d_in[18];
  const float* f2b2 = (const float*)d_in[19];

  char* ws = (char*)d_ws;
  const size_t MB = 1024 * 1024;
  // workspace (~138 MB; harness provides ~268 MB). af is a SEPARATE buffer
  // (attall waves read other waves' q rows -> aliasing q is a race).
  bf16* q_ = (bf16*)(ws + 0);           // 32MB [32768,512]
  bf16* v1t_ = (bf16*)(ws + 32 * MB);   // 32MB [512,32768]
  bf16* af_ = (bf16*)(ws + 64 * MB);    // 32MB [32768,512]
  bf16* xq_ = (bf16*)(ws + 96 * MB);    // 16MB; rf reuses after q GEMM
  bf16* rf_ = xq_;
  bf16* tf_ = (bf16*)(ws + 112 * MB);   // 16MB
  bf16* k_ = (bf16*)(ws + 128 * MB);    // 2MB [2048,512]
  bf16* xk_ = (bf16*)(ws + 130 * MB);   // 1MB; rc reuses
  bf16* rc_ = xk_;
  bf16* v2t_ = (bf16*)(ws + 131 * MB);  // 2MB [512,2048]; acm reuses
  bf16* acm_ = v2t_;
  bf16* wt_ = (bf16*)(ws + 133 * MB);   // 2MB transposed weights
  float* colp_ = (float*)(ws + 135 * MB);  // 512KB [8][64][256]
  bf16* yc_ = (bf16*)(ws + 136 * MB);   // 1MB
  bf16* tc_ = (bf16*)(ws + 137 * MB);   // 1MB
  bf16* yf_ = q_;  // q dead after attall

  // o2 partials in d_out: [8][64][256][64] fp32 = 32MB inside out_feat
  // (33.5MB); fully overwritten by the final feat GEMM.
  float* out_feat = (float*)d_out;
  float* out_center = out_feat + (size_t)8 * 4096 * 256;
  float* o2p_ = out_feat;

  bf16* WqT = wt_;
  bf16* WkT = WqT + 131072;
  bf16* Wv1T = WkT + 131072;
  bf16* Wv2T = Wv1T + 131072;
  bf16* Wo1T = Wv2T + 131072;
  bf16* Wo2T = Wo1T + 131072;
  bf16* f1W1T = Wo2T + 131072;
  bf16* f1W2T = f1W1T + 65536;
  bf16* f2W1T = f1W2T + 65536;
  bf16* f2W2T = f2W1T + 65536;

  WTArgs wa;
  const float* srcs[10] = {Wq, Wk, Wv1, Wv2, Wo1, Wo2, f1W1, f1W2, f2W1, f2W2};
  bf16* dsts[10] = {WqT, WkT, Wv1T, Wv2T, Wo1T, Wo2T, f1W1T, f1W2T, f2W1T, f2W2T};
  int Ks[10] = {256, 256, 256, 256, 512, 512, 256, 256, 256, 256};
  int Ns[10] = {512, 512, 512, 512, 256, 256, 256, 256, 256, 256};
  for (int i = 0; i < 10; ++i) {
    wa.src[i] = srcs[i];
    wa.dst[i] = dsts[i];
    wa.K[i] = Ks[i];
    wa.N[i] = Ns[i];
  }

  wtrans_kernel<<<dim3(8, 8, 10), 256, 0, stream>>>(wa);
  prep_xq_kernel<<<dim3(64, 4, 8), 256, 0, stream>>>(feat, pos, xq_);
  addvec_kernel<<<dim3(512), 256, 0, stream>>>(center, cpos, xk_, 131072);

  // q+k projections in one dispatch
  gemm_dx_kernel<0, bf16, bf16, bf16, bf16><<<dim3(272, 4), 256, 0, stream>>>(
      xq_, WqT, q_, nullptr, nullptr, xk_, WkT, k_, nullptr, nullptr, 256, 512,
      256);
  // v1t+v2t (transposed via swapped GEMM) in one dispatch
  gemm_dy_kernel<0, bf16, bf16, bf16, float><<<dim3(4, 272), 256, 0, stream>>>(
      Wv1T, feat, v1t_, Wv2T, center, v2t_, 256, 32768, 2048, 256);

  // the entire attention
  attall_kernel<<<dim3(8, 64), 256, 0, stream>>>(q_, k_, v1t_, v2t_, af_, o2p_,
                                                 colp_);
  o2red_kernel<<<dim3(4096), 256, 0, stream>>>(o2p_, colp_, acm_);

  // output projections + residual (feat & center fused per dispatch)
  gemm_dx_kernel<2, bf16, float, bf16, bf16><<<dim3(272, 2), 256, 0, stream>>>(
      af_, Wo1T, rf_, feat, nullptr, acm_, Wo2T, rc_, center, nullptr, 256,
      256, 512);
  ln_dual_kernel<<<dim3(8704), 256, 0, stream>>>(rf_, rc_, ln1w, ln1b, ln2w,
                                                 ln2b, yf_, yc_);
  gemm_dx_kernel<1, bf16, bf16, bf16, bf16><<<dim3(272, 2), 256, 0, stream>>>(
      yf_, f1W1T, tf_, nullptr, nullptr, yc_, f2W1T, tc_, nullptr, nullptr,
      256, 256, 256);
  gemm_dx_kernel<3, float, bf16, bf16, bf16><<<dim3(272, 2), 256, 0, stream>>>(
      tf_, f1W2T, out_feat, yf_, f1b2, tc_, f2W2T, out_center, yc_, f2b2, 256,
      256, 256);
}